// Round 2
// baseline (72.432 us; speedup 1.0000x reference)
//
#include <hip/hip_runtime.h>

// 6-qubit circuit, 4 lanes per sample.
// Amp index a (6 bits): qubit w <-> bit (5-w).
//   bits 5..2 -> local index t (qubits 0..3 <-> local bits 3..0), 16 amps/lane
//   bits 1..0 -> lane sub-id (qubit 4 <-> sub bit1, qubit 5 <-> sub bit0)
// State: re[16], im[16] in registers per lane. Cross-lane gates via shfl.

#define NL 2

__global__ __launch_bounds__(256) void qcirc6_l4_kernel(
    const float* __restrict__ x,        // (B, 4)
    const float* __restrict__ weights,  // (NL, 6)
    const float* __restrict__ bias,     // (2,)
    float* __restrict__ out,            // (B, 4)
    int B)
{
    const int gid = blockIdx.x * blockDim.x + threadIdx.x;
    const int sample = gid >> 2;
    if (sample >= B) return;
    const int lane = threadIdx.x & 63;
    const int sub = lane & 3;

    const float4 xv = reinterpret_cast<const float4*>(x)[sample];
    const float xs[4] = {xv.x, xv.y, xv.z, xv.w};

    float re[16], im[16];
    #pragma unroll
    for (int t = 0; t < 16; ++t) { re[t] = 0.0f; im[t] = 0.0f; }
    re[0] = (sub == 0) ? 1.0f : 0.0f;   // |000000>

    // ---- RX(x[w]) on local qubits 0..3 ----
    #pragma unroll
    for (int w = 0; w < 4; ++w) {
        float s, c;
        __sincosf(xs[w] * 0.5f, &s, &c);
        const int m = 1 << (3 - w);
        #pragma unroll
        for (int t = 0; t < 16; ++t) {
            if (t & m) continue;
            const int j = t | m;
            const float a0r = re[t], a0i = im[t];
            const float a1r = re[j], a1i = im[j];
            re[t] =  c * a0r + s * a1i;
            im[t] =  c * a0i - s * a1r;
            re[j] =  s * a0i + c * a1r;
            im[j] = -s * a0r + c * a1i;
        }
    }

    // RY on a lane-mapped qubit (lmask = 2 for qubit4, 1 for qubit5)
    auto ry_lane = [&](float st, float ct, int lmask) {
        const float sg = (sub & lmask) ? st : -st;   // side1: +st*a0 ; side0: -st*a1
        #pragma unroll
        for (int t = 0; t < 16; ++t) {
            const float pr = __shfl_xor(re[t], lmask, 64);
            const float pi = __shfl_xor(im[t], lmask, 64);
            re[t] = ct * re[t] + sg * pr;
            im[t] = ct * im[t] + sg * pi;
        }
    };

    // RY on a local qubit (bit mask m)
    auto ry_local = [&](float st, float ct, int m) {
        #pragma unroll
        for (int t = 0; t < 16; ++t) {
            if (t & m) continue;
            const int j = t | m;
            const float a0r = re[t], a0i = im[t];
            const float a1r = re[j], a1i = im[j];
            re[t] = ct * a0r - st * a1r;
            im[t] = ct * a0i - st * a1i;
            re[j] = st * a0r + ct * a1r;
            im[j] = st * a0i + ct * a1i;
        }
    };

    // CNOT both-local (control mask cm, target mask tm): register rename
    auto cnot_local = [&](int cm, int tm) {
        #pragma unroll
        for (int t = 0; t < 16; ++t) {
            if ((t & cm) && !(t & tm)) {
                const int j = t | tm;
                float tmp;
                tmp = re[t]; re[t] = re[j]; re[j] = tmp;
                tmp = im[t]; im[t] = im[j]; im[j] = tmp;
            }
        }
    };

    // ---- RY(ancilla_bias) on qubits 4,5 ----
    {
        float st, ct;
        __sincosf(bias[0] * 0.5f, &st, &ct);
        ry_lane(st, ct, 2);                 // qubit 4 -> sub bit1
        __sincosf(bias[1] * 0.5f, &st, &ct);
        ry_lane(st, ct, 1);                 // qubit 5 -> sub bit0
    }

    // ---- layers ----
    const int perm45 = (sub & 2) ? (lane ^ 1) : lane;  // CNOT(4,5) lane pull map
    const bool c50 = (sub & 1) != 0;                   // CNOT(5,0) control

    #pragma unroll
    for (int l = 0; l < NL; ++l) {
        // CNOT ring, in order: (0,1) (1,2) (2,3) (3,4) (4,5) (5,0)
        cnot_local(8, 4);
        cnot_local(4, 2);
        cnot_local(2, 1);
        // CNOT(3,4): control local bit0, target lane bit1 -> swap across xor 2
        #pragma unroll
        for (int t = 1; t < 16; t += 2) {
            re[t] = __shfl_xor(re[t], 2, 64);
            im[t] = __shfl_xor(im[t], 2, 64);
        }
        // CNOT(4,5): lanes with sub bit1 swap sub bit0 -> bpermute pull
        #pragma unroll
        for (int t = 0; t < 16; ++t) {
            re[t] = __shfl(re[t], perm45, 64);
            im[t] = __shfl(im[t], perm45, 64);
        }
        // CNOT(5,0): lanes with sub bit0 swap local t <-> t|8
        #pragma unroll
        for (int t = 0; t < 8; ++t) {
            const int j = t | 8;
            float a, b;
            a = re[t]; b = re[j];
            re[t] = c50 ? b : a;  re[j] = c50 ? a : b;
            a = im[t]; b = im[j];
            im[t] = c50 ? b : a;  im[j] = c50 ? a : b;
        }
        // RY(weights[l, w]) on all qubits (order across qubits commutes)
        float st, ct;
        __sincosf(weights[l * 6 + 0] * 0.5f, &st, &ct); ry_local(st, ct, 8);
        __sincosf(weights[l * 6 + 1] * 0.5f, &st, &ct); ry_local(st, ct, 4);
        __sincosf(weights[l * 6 + 2] * 0.5f, &st, &ct); ry_local(st, ct, 2);
        __sincosf(weights[l * 6 + 3] * 0.5f, &st, &ct); ry_local(st, ct, 1);
        __sincosf(weights[l * 6 + 4] * 0.5f, &st, &ct); ry_lane(st, ct, 2);
        __sincosf(weights[l * 6 + 5] * 0.5f, &st, &ct); ry_lane(st, ct, 1);
    }

    // ---- <Z_w>, w=0..3 (local bits 3..0): per-lane partial then 4-lane butterfly
    float z0 = 0.f, z1 = 0.f, z2 = 0.f, z3 = 0.f;
    #pragma unroll
    for (int t = 0; t < 16; ++t) {
        const float p = re[t] * re[t] + im[t] * im[t];
        z0 += (t & 8) ? -p : p;
        z1 += (t & 4) ? -p : p;
        z2 += (t & 2) ? -p : p;
        z3 += (t & 1) ? -p : p;
    }
    z0 += __shfl_xor(z0, 1, 64); z0 += __shfl_xor(z0, 2, 64);
    z1 += __shfl_xor(z1, 1, 64); z1 += __shfl_xor(z1, 2, 64);
    z2 += __shfl_xor(z2, 1, 64); z2 += __shfl_xor(z2, 2, 64);
    z3 += __shfl_xor(z3, 1, 64); z3 += __shfl_xor(z3, 2, 64);

    const float zsel = (sub == 0) ? z0 : (sub == 1) ? z1 : (sub == 2) ? z2 : z3;
    out[sample * 4 + sub] = zsel;   // 64 lanes -> 256 B contiguous
}

extern "C" void kernel_launch(void* const* d_in, const int* in_sizes, int n_in,
                              void* d_out, int out_size, void* d_ws, size_t ws_size,
                              hipStream_t stream) {
    const float* x       = (const float*)d_in[0];  // (B, 4)
    const float* weights = (const float*)d_in[1];  // (2, 6)
    const float* bias    = (const float*)d_in[2];  // (2,)
    float* out = (float*)d_out;                    // (B, 4)
    const int B = in_sizes[0] / 4;
    const int threads = B * 4;
    qcirc6_l4_kernel<<<(threads + 255) / 256, 256, 0, stream>>>(x, weights, bias, out, B);
}

// Round 3
// 63.590 us; speedup vs baseline: 1.1390x; 1.1390x over previous
//
#include <hip/hip_runtime.h>

// 6-qubit circuit, 4 lanes per sample, DPP cross-lane, packed-fp32 math.
//
// Amp index a (6 bits, qubit w <-> bit (5-w)):
//   bits 5..2 -> local index t (qubits 0..3 <-> local bits 3..0): 16 amps/lane
//   bits 1..0 -> lane sub-id   (qubit 4 <-> sub bit1, qubit 5 <-> sub bit0)
// Each amp held as v2f {re, im}; all post-encoding gates are real, so re/im
// evolve identically -> v_pk_fma_f32. Cross-lane = quad-local DPP permutes.

#define NL 2

typedef float v2f __attribute__((ext_vector_type(2)));

template<int CTRL>
__device__ __forceinline__ float dppf(float v) {
    return __int_as_float(__builtin_amdgcn_update_dpp(
        0, __float_as_int(v), CTRL, 0xF, 0xF, true));
}
template<int CTRL>
__device__ __forceinline__ v2f dpp2(v2f v) {
    v2f r; r.x = dppf<CTRL>(v.x); r.y = dppf<CTRL>(v.y); return r;
}
__device__ __forceinline__ v2f splat(float f) { v2f r; r.x = f; r.y = f; return r; }

// quad_perm ctrl bytes
#define QP_XOR1  0xB1   // [1,0,3,2]
#define QP_XOR2  0x4E   // [2,3,0,1]
#define QP_C45   0xB4   // [0,1,3,2]  sub2<->sub3
#define QP_BC0   0x00
#define QP_BC1   0x55
#define QP_BC2   0xAA
#define QP_BC3   0xFF

__global__ __launch_bounds__(256) void qcirc6_dpp_kernel(
    const float* __restrict__ x,        // (B, 4)
    const float* __restrict__ weights,  // (NL, 6)
    const float* __restrict__ bias,     // (2,)
    float* __restrict__ out,            // (B, 4)
    int B)
{
    const int gid = blockIdx.x * blockDim.x + threadIdx.x;
    const int sample = gid >> 2;
    if (sample >= B) return;
    const int sub = gid & 3;

    // ---- per-lane sincos of own feature, quad-broadcast ----
    float sh, ch;
    __sincosf(x[gid] * 0.5f, &sh, &ch);
    const float c0 = dppf<QP_BC0>(ch), s0 = dppf<QP_BC0>(sh);
    const float c1 = dppf<QP_BC1>(ch), s1 = dppf<QP_BC1>(sh);
    const float c2 = dppf<QP_BC2>(ch), s2 = dppf<QP_BC2>(sh);
    const float c3 = dppf<QP_BC3>(ch), s3 = dppf<QP_BC3>(sh);

    // ---- ancilla RY(bias) on |0>: lane factor (real) ----
    float sb0, cb0, sb1, cb1;
    __sincosf(bias[0] * 0.5f, &sb0, &cb0);
    __sincosf(bias[1] * 0.5f, &sb1, &cb1);
    const float laneF = ((sub & 2) ? sb0 : cb0) * ((sub & 1) ? sb1 : cb1);

    // ---- product-state init: amp[t] = (-i)^popc(t) * prod(c/s) * laneF ----
    const float v01[4] = {c0 * c1, c0 * s1, s0 * c1, s0 * s1};
    const float v23[4] = {c2 * c3, c2 * s3, s2 * c3, s2 * s3};

    v2f a[16];
    #pragma unroll
    for (int t = 0; t < 16; ++t) {
        const float v = laneF * v01[t >> 2] * v23[t & 3];
        const int m = ((t & 1) + ((t >> 1) & 1) + ((t >> 2) & 1) + ((t >> 3) & 1)) & 3;
        v2f av;
        if      (m == 0) { av.x =  v;   av.y = 0.f; }
        else if (m == 1) { av.x = 0.f;  av.y = -v;  }
        else if (m == 2) { av.x = -v;   av.y = 0.f; }
        else             { av.x = 0.f;  av.y =  v;  }
        a[t] = av;
    }

    const bool c50 = (sub & 1) != 0;   // CNOT(5,0) control = qubit5 = sub bit0

    // ---- layers ----
    #pragma unroll
    for (int l = 0; l < NL; ++l) {
        // CNOT(0,1),(1,2),(2,3): local register renames
        #pragma unroll
        for (int pass = 0; pass < 3; ++pass) {
            const int cm = 8 >> pass, tm = 4 >> pass;
            #pragma unroll
            for (int t = 0; t < 16; ++t) {
                if ((t & cm) && !(t & tm)) {
                    const int j = t | tm;
                    v2f tmp = a[t]; a[t] = a[j]; a[j] = tmp;
                }
            }
        }
        // CNOT(3,4): control local bit0, target lane bit1 -> odd t cross xor2
        #pragma unroll
        for (int t = 1; t < 16; t += 2) a[t] = dpp2<QP_XOR2>(a[t]);
        // CNOT(4,5): sub2<->sub3 permute of everything
        #pragma unroll
        for (int t = 0; t < 16; ++t) a[t] = dpp2<QP_C45>(a[t]);

        float st, ct;
        // RY(q0) fused with CNOT(5,0): pairs (t, t|8)
        __sincosf(weights[l * 6 + 0] * 0.5f, &st, &ct);
        {
            const v2f al = splat(c50 ? -st : ct);
            const v2f be = splat(c50 ?  ct : -st);
            const v2f ga = splat(c50 ?  ct : st);
            const v2f de = splat(c50 ?  st : ct);
            #pragma unroll
            for (int t = 0; t < 8; ++t) {
                const int j = t | 8;
                const v2f a0 = a[t], a1 = a[j];
                a[t] = al * a0 + be * a1;
                a[j] = ga * a0 + de * a1;
            }
        }
        // RY(q1..q3): local masks 4,2,1
        #pragma unroll
        for (int w = 1; w < 4; ++w) {
            __sincosf(weights[l * 6 + w] * 0.5f, &st, &ct);
            const v2f ctv = splat(ct), stv = splat(st);
            const int m = 8 >> w;
            #pragma unroll
            for (int t = 0; t < 16; ++t) {
                if (t & m) continue;
                const int j = t | m;
                const v2f a0 = a[t], a1 = a[j];
                a[t] = ctv * a0 - stv * a1;
                a[j] = stv * a0 + ctv * a1;
            }
        }
        // RY(q4): lane bit1 (xor2) ; RY(q5): lane bit0 (xor1)
        __sincosf(weights[l * 6 + 4] * 0.5f, &st, &ct);
        {
            const v2f ctv = splat(ct), sgv = splat((sub & 2) ? st : -st);
            #pragma unroll
            for (int t = 0; t < 16; ++t) {
                const v2f p = dpp2<QP_XOR2>(a[t]);
                a[t] = ctv * a[t] + sgv * p;
            }
        }
        __sincosf(weights[l * 6 + 5] * 0.5f, &st, &ct);
        {
            const v2f ctv = splat(ct), sgv = splat((sub & 1) ? st : -st);
            #pragma unroll
            for (int t = 0; t < 16; ++t) {
                const v2f p = dpp2<QP_XOR1>(a[t]);
                a[t] = ctv * a[t] + sgv * p;
            }
        }
    }

    // ---- <Z_w> w=0..3 (local bits 3..0) ----
    float z0 = 0.f, z1 = 0.f, z2 = 0.f, z3 = 0.f;
    #pragma unroll
    for (int t = 0; t < 16; ++t) {
        const v2f sq = a[t] * a[t];
        const float p = sq.x + sq.y;
        z0 += (t & 8) ? -p : p;
        z1 += (t & 4) ? -p : p;
        z2 += (t & 2) ? -p : p;
        z3 += (t & 1) ? -p : p;
    }
    z0 += dppf<QP_XOR1>(z0); z0 += dppf<QP_XOR2>(z0);
    z1 += dppf<QP_XOR1>(z1); z1 += dppf<QP_XOR2>(z1);
    z2 += dppf<QP_XOR1>(z2); z2 += dppf<QP_XOR2>(z2);
    z3 += dppf<QP_XOR1>(z3); z3 += dppf<QP_XOR2>(z3);

    const float zsel = (sub == 0) ? z0 : (sub == 1) ? z1 : (sub == 2) ? z2 : z3;
    out[gid] = zsel;   // gid = sample*4 + sub, fully coalesced
}

extern "C" void kernel_launch(void* const* d_in, const int* in_sizes, int n_in,
                              void* d_out, int out_size, void* d_ws, size_t ws_size,
                              hipStream_t stream) {
    const float* x       = (const float*)d_in[0];  // (B, 4)
    const float* weights = (const float*)d_in[1];  // (2, 6)
    const float* bias    = (const float*)d_in[2];  // (2,)
    float* out = (float*)d_out;                    // (B, 4)
    const int B = in_sizes[0] / 4;
    const int threads = B * 4;
    qcirc6_dpp_kernel<<<(threads + 255) / 256, 256, 0, stream>>>(x, weights, bias, out, B);
}